// Round 1
// baseline (9480.184 us; speedup 1.0000x reference)
//
#include <hip/hip_runtime.h>
#include <stdint.h>

#define B_ 16
#define T_ 2048
#define I_ 512
#define H_ 512
#define G4 2048
#define NW 64          // workgroups in the persistent kernel
#define JJ 8           // h-columns owned per WG (H_/NW)

typedef __bf16 bf16x8 __attribute__((ext_vector_type(8)));
typedef __bf16 bf16x4 __attribute__((ext_vector_type(4)));
typedef float  f32x4  __attribute__((ext_vector_type(4)));

__device__ __forceinline__ float sigm(float x) {
    // 1/(1+exp(-x)) via exp2/rcp; exact enough (~1ulp hw ops)
    return __builtin_amdgcn_rcpf(1.f + __builtin_amdgcn_exp2f(-1.44269504f * x));
}
__device__ __forceinline__ float tanh_f(float x) {
    float xc = fmaxf(x, -40.f);                       // avoid inf*0 = NaN
    float e  = __builtin_amdgcn_exp2f(-2.88539008f * xc);
    return (1.f - e) * __builtin_amdgcn_rcpf(1.f + e);
}

// ---- prep: x [B][T][I] fp32 -> xp [T][B][I] bf16 ----
__global__ void pack_x(const float* __restrict__ x, __bf16* __restrict__ xp) {
    int q = blockIdx.x * 256 + threadIdx.x;   // 4 elems each
    int o = q * 4;                            // dst linear over [T][B][I]
    int i  = o & (I_ - 1);
    int tb = o >> 9;
    int b  = tb & (B_ - 1);
    int t  = tb >> 4;
    float4 v = *(const float4*)(x + ((size_t)(b * T_ + t) * I_ + i));
    *(bf16x4*)(xp + o) = (bf16x4){(__bf16)v.x, (__bf16)v.y, (__bf16)v.z, (__bf16)v.w};
}

// ---- prep: pack Wi/Wh rows per-WG: wp[w][n][k], n = gate*8 + jj, row = gate*512 + w*8 + jj
__global__ void pack_w(const float* __restrict__ Wi, const float* __restrict__ Wh,
                       __bf16* __restrict__ wip, __bf16* __restrict__ whp) {
    int q = blockIdx.x * 256 + threadIdx.x;   // total 2*64*32*128 threads, 4 k each
    int k = (q & 127) * 4;  q >>= 7;
    int n = q & 31;         q >>= 5;
    int w = q & 63;         q >>= 6;
    int mat = q;
    int row = (n >> 3) * 512 + w * JJ + (n & 7);
    const float* src = (mat ? Wh : Wi) + (size_t)row * 512 + k;
    float4 v = *(const float4*)src;
    __bf16* dst = (mat ? whp : wip) + ((size_t)(w * 32 + n) * 512 + k);
    *(bf16x4*)dst = (bf16x4){(__bf16)v.x, (__bf16)v.y, (__bf16)v.z, (__bf16)v.w};
}

// ---- prep: h0 -> hbuf[0] (bf16), bias pack biasp[w*32+n] = bi[row]+bh[row]
__global__ void prep_small(const float* __restrict__ h0, const float* __restrict__ bi,
                           const float* __restrict__ bh, __bf16* __restrict__ hbuf,
                           float* __restrict__ biasp) {
    int i = blockIdx.x * 256 + threadIdx.x;   // 8192 threads
    hbuf[i] = (__bf16)h0[i];
    if (i < G4) {
        int w = i >> 5, n = i & 31;
        int row = (n >> 3) * 512 + w * JJ + (n & 7);
        biasp[i] = bi[row] + bh[row];
    }
}

// ---- persistent recurrent kernel ----
__global__ __launch_bounds__(256) void lstm_main(
    const float* __restrict__ c0,
    const __bf16* __restrict__ xp,
    const __bf16* __restrict__ wip,
    const __bf16* __restrict__ whp,
    const float* __restrict__ biasp,
    __bf16* hbuf,                 // [2][B_][H_]
    unsigned* bar_count, unsigned* bar_flag,
    float* __restrict__ out)
{
    const int w    = blockIdx.x;
    const int tid  = threadIdx.x;
    const int wave = tid >> 6;
    const int lane = tid & 63;
    const int quad = lane >> 4;
    const int n16  = lane & 15;

    __shared__ float red[8 * 256];   // [r][tid], conflict-free stride

    // persistent weight fragments in VGPRs: this wave covers k in [wave*128, wave*128+128)
    const int kbase = wave * 128;
    bf16x8 bwx[2][4], bwh[2][4];
#pragma unroll
    for (int tile = 0; tile < 2; ++tile)
#pragma unroll
        for (int kc = 0; kc < 4; ++kc) {
            int k0 = kbase + kc * 32 + quad * 8;
            size_t idx = ((size_t)(w * 32 + tile * 16 + n16)) * 512 + k0;
            bwx[tile][kc] = *(const bf16x8*)(wip + idx);
            bwh[tile][kc] = *(const bf16x8*)(whp + idx);
        }

    // c-state: canonical lanes are wave0, n16<8 (32 lanes x 4 regs = 16 batches x 8 cols)
    const int col = w * JJ + (n16 & 7);
    float creg[4];
#pragma unroll
    for (int r = 0; r < 4; ++r) {
        int m = quad * 4 + r;
        creg[r] = c0[(size_t)m * H_ + col];
    }
    const float bias0 = biasp[w * 32 + n16];
    const float bias1 = biasp[w * 32 + 16 + n16];

    float* outHT = out + (size_t)B_ * T_ * H_;
    float* outCT = outHT + (size_t)B_ * H_;

    for (int t = 0; t < T_; ++t) {
        const unsigned long long* hr64 =
            (const unsigned long long*)(hbuf + (size_t)(t & 1) * (B_ * H_));

        f32x4 acc0 = {0.f, 0.f, 0.f, 0.f}, acc1 = {0.f, 0.f, 0.f, 0.f};
#pragma unroll
        for (int kc = 0; kc < 4; ++kc) {
            int k0 = kbase + kc * 32 + quad * 8;
            bf16x8 ax = *(const bf16x8*)(xp + ((size_t)(t * B_ + n16)) * I_ + k0);
            union { unsigned long long u[2]; bf16x8 v; } ah;
            size_t h64 = ((size_t)n16 * H_ + k0) >> 2;
            ah.u[0] = __hip_atomic_load(hr64 + h64,     __ATOMIC_RELAXED, __HIP_MEMORY_SCOPE_AGENT);
            ah.u[1] = __hip_atomic_load(hr64 + h64 + 1, __ATOMIC_RELAXED, __HIP_MEMORY_SCOPE_AGENT);
            acc0 = __builtin_amdgcn_mfma_f32_16x16x32_bf16(ax,   bwx[0][kc], acc0, 0, 0, 0);
            acc0 = __builtin_amdgcn_mfma_f32_16x16x32_bf16(ah.v, bwh[0][kc], acc0, 0, 0, 0);
            acc1 = __builtin_amdgcn_mfma_f32_16x16x32_bf16(ax,   bwx[1][kc], acc1, 0, 0, 0);
            acc1 = __builtin_amdgcn_mfma_f32_16x16x32_bf16(ah.v, bwh[1][kc], acc1, 0, 0, 0);
        }

        // cross-wave K reduction through LDS
#pragma unroll
        for (int r = 0; r < 4; ++r) {
            red[r * 256 + tid]       = acc0[r];
            red[(4 + r) * 256 + tid] = acc1[r];
        }
        __syncthreads();

        if (wave == 0) {
            float g8[8];
#pragma unroll
            for (int r = 0; r < 8; ++r)
                g8[r] = red[r * 256 + lane] + red[r * 256 + 64 + lane] +
                        red[r * 256 + 128 + lane] + red[r * 256 + 192 + lane];

            unsigned short* hw16 =
                (unsigned short*)(hbuf + (size_t)((t + 1) & 1) * (B_ * H_));
#pragma unroll
            for (int r = 0; r < 4; ++r) {
                float v0 = g8[r]     + bias0;   // tile0: i (n16<8) | f (n16>=8)
                float v1 = g8[4 + r] + bias1;   // tile1: g (n16<8) | o (n16>=8)
                float p0 = __shfl_xor(v0, 8, 64);
                float p1 = __shfl_xor(v1, 8, 64);
                if (n16 < 8) {
                    float ig = sigm(v0), fg = sigm(p0), gg = tanh_f(v1), og = sigm(p1);
                    float c = fg * creg[r] + ig * gg;
                    creg[r] = c;
                    float h = og * tanh_f(c);
                    int m = quad * 4 + r;
                    out[((size_t)m * T_ + t) * H_ + col] = h;
                    __bf16 hb = (__bf16)h;
                    __hip_atomic_store(hw16 + m * H_ + col,
                                       __builtin_bit_cast(unsigned short, hb),
                                       __ATOMIC_RELAXED, __HIP_MEMORY_SCOPE_AGENT);
                    if (t == T_ - 1) {
                        outHT[(size_t)m * H_ + col] = h;
                        outCT[(size_t)m * H_ + col] = c;
                    }
                }
            }
        }

        if (t == T_ - 1) break;   // no one reads hbuf after the final step

        // grid barrier: monotone counter + flag (RELEASE add drains wave0's h-stores)
        if (tid == 0) {
            unsigned old = __hip_atomic_fetch_add(bar_count, 1u,
                                                  __ATOMIC_RELEASE, __HIP_MEMORY_SCOPE_AGENT);
            if (old == (unsigned)(NW * (t + 1) - 1))
                __hip_atomic_store(bar_flag, (unsigned)(t + 1),
                                   __ATOMIC_RELEASE, __HIP_MEMORY_SCOPE_AGENT);
            while (__hip_atomic_load(bar_flag, __ATOMIC_RELAXED,
                                     __HIP_MEMORY_SCOPE_AGENT) < (unsigned)(t + 1))
                __builtin_amdgcn_s_sleep(1);
        }
        __syncthreads();
    }
}

extern "C" void kernel_launch(void* const* d_in, const int* in_sizes, int n_in,
                              void* d_out, int out_size, void* d_ws, size_t ws_size,
                              hipStream_t stream) {
    const float* x  = (const float*)d_in[0];
    const float* h0 = (const float*)d_in[1];
    const float* c0 = (const float*)d_in[2];
    const float* Wi = (const float*)d_in[3];
    const float* bi = (const float*)d_in[4];
    const float* Wh = (const float*)d_in[5];
    const float* bh = (const float*)d_in[6];
    float* out = (float*)d_out;

    char* ws = (char*)d_ws;
    __bf16*  xp    = (__bf16*)ws;                                    // 32 MB
    __bf16*  wip   = (__bf16*)(ws + 33554432);                       // 2 MB
    __bf16*  whp   = (__bf16*)(ws + 33554432 + 2097152);             // 2 MB
    float*   biasp = (float*) (ws + 33554432 + 4194304);             // 8 KB
    __bf16*  hbuf  = (__bf16*)(ws + 33554432 + 4194304 + 8192);      // 2x16 KB
    unsigned* bar  = (unsigned*)(ws + 33554432 + 4194304 + 8192 + 65536);

    hipMemsetAsync(bar, 0, 256, stream);
    pack_x<<<16384, 256, 0, stream>>>(x, xp);
    pack_w<<<2048, 256, 0, stream>>>(Wi, Wh, wip, whp);
    prep_small<<<32, 256, 0, stream>>>(h0, bi, bh, hbuf, biasp);

    unsigned* bar_count = bar;
    unsigned* bar_flag  = bar + 32;   // 128 B apart
    void* args[] = { (void*)&c0, (void*)&xp, (void*)&wip, (void*)&whp, (void*)&biasp,
                     (void*)&hbuf, (void*)&bar_count, (void*)&bar_flag, (void*)&out };
    hipLaunchCooperativeKernel((void*)lstm_main, dim3(NW), dim3(256), args, 0, stream);
}